// Round 7
// baseline (445.185 us; speedup 1.0000x reference)
//
#include <hip/hip_runtime.h>

#define NN 8192
#define RPB 8                  // rows per block
#define NBLK (NN / RPB)        // 1024 blocks
#define SLICE2 32              // second-stage slice count

// ws layout (floats): wv[NN] | diag[NN] | partial[NBLK*NN] | partial2[SLICE2*NN]

// Single-pass kernel: block b streams rows [8b, 8b+8) cooperatively, one row
// at a time, matrix read from HBM EXACTLY ONCE. Each thread holds its 32
// columns in registers (8 float4); block-reduces sum of squares with ONE
// barrier per row (red[] double-buffered, every thread redundantly computes
// the total and w_r); diag/V preloaded to LDS so no dependent global load
// sits in the critical section. __launch_bounds__(256,4) caps VGPRs at 128
// so 4 blocks/CU hide the barrier latency.
__global__ void __launch_bounds__(256, 4)
main_pass(const float* __restrict__ ts,
          const float* __restrict__ state,
          float* __restrict__ wv,
          float* __restrict__ diag,
          float* __restrict__ partial)
{
    __shared__ float red[2][4];
    __shared__ float sd2[RPB];   // diag^2 per row
    __shared__ float sv[RPB];    // V per row

    const int tid  = threadIdx.x;
    const int lane = tid & 63;
    const int wid  = tid >> 6;
    const int row0 = blockIdx.x * RPB;

    if (tid < RPB) {
        const float d = ts[(size_t)(row0 + tid) * NN + (row0 + tid)];
        sd2[tid] = d * d;
        sv[tid]  = state[3 * (row0 + tid) + 2];
    }

    float4 acc[8];
    #pragma unroll
    for (int k = 0; k < 8; ++k) acc[k] = make_float4(0.f, 0.f, 0.f, 0.f);

    float4 cur[8], nxt[8];
    {
        const float4* rp = (const float4*)(ts + (size_t)row0 * NN);
        #pragma unroll
        for (int k = 0; k < 8; ++k) cur[k] = rp[tid + k * 256];
    }

    #pragma unroll
    for (int r = 0; r < RPB; ++r) {
        const int row = row0 + r;
        if (r + 1 < RPB) {                 // prefetch next row before the barrier
            const float4* np = (const float4*)(ts + (size_t)(row + 1) * NN);
            #pragma unroll
            for (int k = 0; k < 8; ++k) nxt[k] = np[tid + k * 256];
        }
        // partial sum of squares over this thread's 32 columns
        float s = 0.f;
        #pragma unroll
        for (int k = 0; k < 8; ++k) {
            float4 v = cur[k];
            s += v.x * v.x + v.y * v.y + v.z * v.z + v.w * v.w;
        }
        #pragma unroll
        for (int off = 32; off; off >>= 1) s += __shfl_down(s, off);
        const int p = r & 1;
        if (lane == 0) red[p][wid] = s;
        __syncthreads();                   // the ONLY barrier this row
        const float total = red[p][0] + red[p][1] + red[p][2] + red[p][3];
        const float d2 = sd2[r];
        const float wr = fminf(d2 / (total - d2), 1.0f) * sv[r];
        if (tid == 0) { wv[row] = wr; diag[row] = d2; }
        #pragma unroll
        for (int k = 0; k < 8; ++k) {      // weighted accumulate from registers
            float4 v = cur[k];
            acc[k].x += wr * v.x * v.x;
            acc[k].y += wr * v.y * v.y;
            acc[k].z += wr * v.z * v.z;
            acc[k].w += wr * v.w * v.w;
        }
        if (r + 1 < RPB) {
            #pragma unroll
            for (int k = 0; k < 8; ++k) cur[k] = nxt[k];
        }
    }
    // write the block's partial slice (32 KB, coalesced float4)
    float4* po = (float4*)(partial + (size_t)blockIdx.x * NN);
    #pragma unroll
    for (int k = 0; k < 8; ++k) po[tid + k * 256] = acc[k];
}

// Reduce 1024 slices -> 32 slices. grid(8, 32): x = col group (1024 cols),
// y = slice group (sums 32 slices). float4 coalesced; source is L2/L3-hot.
__global__ void __launch_bounds__(256)
reduce1(const float* __restrict__ partial, float* __restrict__ partial2)
{
    const int col = blockIdx.x * 1024 + threadIdx.x * 4;
    const float* base = partial + (size_t)blockIdx.y * 32 * NN + col;
    float4 acc = {0.f, 0.f, 0.f, 0.f};
    #pragma unroll 8
    for (int k = 0; k < 32; ++k) {
        float4 v = *(const float4*)(base + (size_t)k * NN);
        acc.x += v.x; acc.y += v.y; acc.z += v.z; acc.w += v.w;
    }
    *(float4*)(partial2 + (size_t)blockIdx.y * NN + col) = acc;
}

// Reduce 32 slices + all O(N) elementwise math.
__global__ void __launch_bounds__(256)
finalize(const float* __restrict__ state,
         const float* __restrict__ betas,
         const float* __restrict__ deltas,
         const float* __restrict__ cs,
         const float* __restrict__ ps,
         const float* __restrict__ wv,
         const float* __restrict__ diag,
         const float* __restrict__ partial2,
         float* __restrict__ out)
{
    const int j = blockIdx.x * 256 + threadIdx.x;
    float coup = 0.f;
    #pragma unroll 8
    for (int k = 0; k < SLICE2; ++k) coup += partial2[(size_t)k * NN + j];
    const float dj = diag[j];
    coup -= wv[j] * dj;                                // remove i==j term

    const float U = state[3 * j + 0];
    const float I = state[3 * j + 1];
    const float V = state[3 * j + 2];
    const float b2 = betas[j] * betas[j];
    const float d2 = deltas[j] * deltas[j];
    const float p2 = ps[j] * ps[j];
    const float c2 = cs[j] * cs[j];
    const float bUV = b2 * U * V;

    out[3 * j + 0] = -bUV;
    out[3 * j + 1] = bUV - d2 * I;
    out[3 * j + 2] = p2 * I - c2 * V - dj + coup;
}

extern "C" void kernel_launch(void* const* d_in, const int* in_sizes, int n_in,
                              void* d_out, int out_size, void* d_ws, size_t ws_size,
                              hipStream_t stream) {
    // inputs: 0:t 1:state 2:betas 3:deltas 4:cs 5:ps 6:ts
    const float* state  = (const float*)d_in[1];
    const float* betas  = (const float*)d_in[2];
    const float* deltas = (const float*)d_in[3];
    const float* cs     = (const float*)d_in[4];
    const float* ps     = (const float*)d_in[5];
    const float* ts     = (const float*)d_in[6];
    float* out = (float*)d_out;

    float* wv       = (float*)d_ws;
    float* diag     = wv + NN;
    float* partial  = diag + NN;
    float* partial2 = partial + (size_t)NBLK * NN;

    main_pass<<<NBLK, 256, 0, stream>>>(ts, state, wv, diag, partial);
    reduce1<<<dim3(8, SLICE2), 256, 0, stream>>>(partial, partial2);
    finalize<<<NN / 256, 256, 0, stream>>>(state, betas, deltas, cs, ps,
                                           wv, diag, partial2, out);
}